// Round 1
// baseline (246.859 us; speedup 1.0000x reference)
//
#include <hip/hip_runtime.h>
#include <stdint.h>

#define BB 16
#define NN 2048
#define DD 64

typedef short bf8_t __attribute__((ext_vector_type(8)));   // 8 bf16 values (4 VGPRs)
typedef float f32x4 __attribute__((ext_vector_type(4)));

__device__ __forceinline__ unsigned short f2b(float f) {
    // round-to-nearest-even fp32 -> bf16 (inputs are finite; no NaN handling needed)
    unsigned int u = __builtin_bit_cast(unsigned int, f);
    unsigned int r = (u + 0x7FFFu + ((u >> 16) & 1u)) >> 16;
    return (unsigned short)r;
}

// ---------------------------------------------------------------------------
// Kernel 1: per (b, 64-row tile):
//   xh[b][n][k]  = bf16(x)                      (MFMA A/B operand for mup)
//   rnorm[b][n]  = 1/||x[b,n]||  (fp32, exact)
//   sT[b][e][n]  = bf16(x[b,n,:] @ W[:,e])      (transposed so GEMM2 B-frags are
//                                                contiguous 16B rows in LDS)
// ---------------------------------------------------------------------------
__global__ __launch_bounds__(256) void prep_kernel(
    const float* __restrict__ x, const float* __restrict__ w,
    unsigned short* __restrict__ xh, unsigned short* __restrict__ sT,
    float* __restrict__ rnorm)
{
    __shared__ __attribute__((aligned(16))) float Wl[DD * DD];
    __shared__ __attribute__((aligned(16))) float xrow[4][DD];
    __shared__ __attribute__((aligned(16))) unsigned short stile[64][72];

    const int t = threadIdx.x;
    const int wv = t >> 6, lane = t & 63;
    const int b = blockIdx.x >> 5;          // 16 batches * 32 tiles
    const int i0 = (blockIdx.x & 31) * 64;

    #pragma unroll
    for (int i = 0; i < 16; ++i) Wl[t + i * 256] = w[t + i * 256];
    __syncthreads();

    for (int r = 0; r < 16; ++r) {
        const int n = wv * 16 + r;
        const int grow = b * NN + i0 + n;
        const float xv = x[grow * DD + lane];
        float s = xv * xv;
        #pragma unroll
        for (int off = 32; off; off >>= 1) s += __shfl_xor(s, off);
        if (lane == 0) rnorm[grow] = 1.0f / sqrtf(s);
        xh[grow * DD + lane] = f2b(xv);
        xrow[wv][lane] = xv;                 // same-wave LDS ops are in-order
        float acc = 0.f;
        #pragma unroll
        for (int k = 0; k < DD; ++k) acc = fmaf(xrow[wv][k], Wl[k * DD + lane], acc);
        stile[n][lane] = f2b(acc);           // support for row n, col=lane
    }
    __syncthreads();

    // write sT[b][e][i0 .. i0+63], packed u32 (2 bf16 per store)
    const int e = t & 63, g = t >> 6;
    unsigned int* dst = (unsigned int*)(sT + ((b * DD + e) * NN + i0 + g * 16));
    #pragma unroll
    for (int j = 0; j < 8; ++j) {
        unsigned int lo = stile[g * 16 + 2 * j][e];
        unsigned int hi = stile[g * 16 + 2 * j + 1][e];
        dst[j] = lo | (hi << 16);
    }
}

// ---------------------------------------------------------------------------
// Kernel 2: fused flash-style GCN.
// Block = (b, i-tile of 64 rows), 4 waves x 16-row strips. m-loop in 64-chunks:
//   mup = Xi @ Xm^T (MFMA 16x16x32 bf16, K=64)  -> scale by rni*rnm*att*mask
//   -> bf16 -> per-wave LDS (C-layout -> A-layout transform)
//   -> out += Adj @ S (B-frags from transposed SmT tile)
// LDS tiles padded to stride 72 (144B): row-major lane&15-row reads alias only
// 2-way across banks (free per m136).
// ---------------------------------------------------------------------------
__global__ __launch_bounds__(256) void gcn_kernel(
    const unsigned short* __restrict__ xh, const unsigned short* __restrict__ sT,
    const float* __restrict__ rnorm, const float* __restrict__ att,
    const int* __restrict__ mask, const float* __restrict__ bias,
    float* __restrict__ out)
{
    __shared__ __attribute__((aligned(16))) unsigned short Xi[64 * 72];
    __shared__ __attribute__((aligned(16))) unsigned short Xm[64 * 72];
    __shared__ __attribute__((aligned(16))) unsigned short Sm[64 * 72];
    __shared__ __attribute__((aligned(16))) unsigned short Adj[4][16 * 72];

    const int t = threadIdx.x;
    const int wv = t >> 6;
    const int lane = t & 63;
    const int c = lane & 15, q = lane >> 4;
    const int b = blockIdx.x >> 5;
    const int i0 = (blockIdx.x & 31) * 64;

    // stage Xi: 64 rows x 128B, 16B chunks, coalesced
    #pragma unroll
    for (int i = 0; i < 2; ++i) {
        const int chunk = t + i * 256;               // 0..511
        const int row = chunk >> 3, ch = chunk & 7;
        *(uint4*)&Xi[row * 72 + ch * 8] =
            *(const uint4*)(xh + ((b * NN + i0 + row) * DD + ch * 8));
    }

    float rni[4];
    #pragma unroll
    for (int r = 0; r < 4; ++r) rni[r] = rnorm[b * NN + i0 + wv * 16 + q * 4 + r];
    float bs[4];
    #pragma unroll
    for (int cb = 0; cb < 4; ++cb) bs[cb] = bias[cb * 16 + c];

    f32x4 acc[4];
    #pragma unroll
    for (int cb = 0; cb < 4; ++cb) acc[cb] = (f32x4){0.f, 0.f, 0.f, 0.f};

    const int irow_g = i0 + wv * 16;

    for (int mchunk = 0; mchunk < 32; ++mchunk) {
        const int m0 = mchunk * 64;
        __syncthreads();   // prev-iter Xm/Sm reads done (also orders Xi staging on iter 0)
        #pragma unroll
        for (int i = 0; i < 2; ++i) {
            const int chunk = t + i * 256;
            const int row = chunk >> 3, ch = chunk & 7;
            *(uint4*)&Xm[row * 72 + ch * 8] =
                *(const uint4*)(xh + ((b * NN + m0 + row) * DD + ch * 8));
            *(uint4*)&Sm[row * 72 + ch * 8] =
                *(const uint4*)(sT + ((b * DD + row) * NN + m0 + ch * 8));
        }
        __syncthreads();

        // att*mask for this wave's 16x64 adjacency strip (C/D layout coords)
        float am[16];
        #pragma unroll
        for (int cb = 0; cb < 4; ++cb) {
            #pragma unroll
            for (int r = 0; r < 4; ++r) {
                const int gi = (irow_g + q * 4 + r) * NN + (m0 + cb * 16 + c);
                am[cb * 4 + r] = att[gi] * (float)mask[gi];
            }
        }
        float rnm[4];
        #pragma unroll
        for (int cb = 0; cb < 4; ++cb) rnm[cb] = rnorm[b * NN + m0 + cb * 16 + c];

        // ---- GEMM1: mup strip = Xi[16 x 64] @ Xm^T  (A row = lane&15, k = q*8+j)
        const bf8_t a0 = *(const bf8_t*)&Xi[(wv * 16 + c) * 72 + q * 8];
        const bf8_t a1 = *(const bf8_t*)&Xi[(wv * 16 + c) * 72 + 32 + q * 8];
        f32x4 mup[4];
        #pragma unroll
        for (int cb = 0; cb < 4; ++cb) {
            const bf8_t b0 = *(const bf8_t*)&Xm[(cb * 16 + c) * 72 + q * 8];
            const bf8_t b1 = *(const bf8_t*)&Xm[(cb * 16 + c) * 72 + 32 + q * 8];
            f32x4 z = (f32x4){0.f, 0.f, 0.f, 0.f};
            z = __builtin_amdgcn_mfma_f32_16x16x32_bf16(a0, b0, z, 0, 0, 0);
            z = __builtin_amdgcn_mfma_f32_16x16x32_bf16(a1, b1, z, 0, 0, 0);
            mup[cb] = z;
        }

        // ---- adjacency = mup * rni * rnm * (att*mask) -> bf16 -> per-wave LDS
        // C/D layout: row = q*4+r, col = cb*16+c  (verified m89/m91)
        #pragma unroll
        for (int cb = 0; cb < 4; ++cb) {
            #pragma unroll
            for (int r = 0; r < 4; ++r) {
                const float v = mup[cb][r] * rni[r] * rnm[cb] * am[cb * 4 + r];
                Adj[wv][(q * 4 + r) * 72 + cb * 16 + c] = f2b(v);
            }
        }
        // same-wave DS ordering guarantees write->read visibility (no barrier:
        // Adj is private to this wave)

        // ---- GEMM2: out strip += Adj[16 x 64] @ S[64 x 64]
        const bf8_t p0 = *(const bf8_t*)&Adj[wv][c * 72 + q * 8];
        const bf8_t p1 = *(const bf8_t*)&Adj[wv][c * 72 + 32 + q * 8];
        #pragma unroll
        for (int cb = 0; cb < 4; ++cb) {
            const bf8_t s0 = *(const bf8_t*)&Sm[(cb * 16 + c) * 72 + q * 8];
            const bf8_t s1 = *(const bf8_t*)&Sm[(cb * 16 + c) * 72 + 32 + q * 8];
            acc[cb] = __builtin_amdgcn_mfma_f32_16x16x32_bf16(p0, s0, acc[cb], 0, 0, 0);
            acc[cb] = __builtin_amdgcn_mfma_f32_16x16x32_bf16(p1, s1, acc[cb], 0, 0, 0);
        }
    }

    // epilogue: direct stores (block owns full K reduction), + bias
    #pragma unroll
    for (int cb = 0; cb < 4; ++cb) {
        #pragma unroll
        for (int r = 0; r < 4; ++r) {
            out[(b * NN + i0 + wv * 16 + q * 4 + r) * DD + cb * 16 + c] =
                acc[cb][r] + bs[cb];
        }
    }
}

extern "C" void kernel_launch(void* const* d_in, const int* in_sizes, int n_in,
                              void* d_out, int out_size, void* d_ws, size_t ws_size,
                              hipStream_t stream) {
    const float* x    = (const float*)d_in[0];   // [16,2048,64]
    const float* w    = (const float*)d_in[1];   // [64,64]
    const float* att  = (const float*)d_in[2];   // [2048,2048]
    const float* bias = (const float*)d_in[3];   // [64]
    const int*   mask = (const int*)d_in[4];     // [2048,2048] int32
    float* out = (float*)d_out;                  // [16,2048,64] fp32

    // workspace carve: xh (4 MB bf16) | sT (4 MB bf16, transposed) | rnorm (128 KB)
    unsigned short* xh = (unsigned short*)d_ws;
    unsigned short* sT = xh + (size_t)BB * NN * DD;
    float* rnorm = (float*)(sT + (size_t)BB * DD * NN);

    prep_kernel<<<dim3(512), dim3(256), 0, stream>>>(x, w, xh, sT, rnorm);
    gcn_kernel<<<dim3(512), dim3(256), 0, stream>>>(xh, sT, rnorm, att, mask, bias, out);
}

// Round 2
// 123.467 us; speedup vs baseline: 1.9994x; 1.9994x over previous
//
#include <hip/hip_runtime.h>
#include <stdint.h>

#define NN 2048

typedef short bf8_t __attribute__((ext_vector_type(8)));   // 8 bf16 (4 VGPRs)
typedef float f32x4 __attribute__((ext_vector_type(4)));

// fp32 -> bf16 RNE, result in TOP 16 bits of return
__device__ __forceinline__ unsigned int rbf(float f) {
    unsigned int u = __builtin_bit_cast(unsigned int, f);
    return u + 0x7FFFu + ((u >> 16) & 1u);
}
__device__ __forceinline__ unsigned short f2b(float f) { return (unsigned short)(rbf(f) >> 16); }
// pack two fp32 -> (bf16(lo) | bf16(hi)<<16)
__device__ __forceinline__ unsigned int pk2(float lo, float hi) {
    return (rbf(lo) >> 16) | (rbf(hi) & 0xFFFF0000u);
}

// ---------------------------------------------------------------------------
// prep_xsb: per (b, 64-row tile nt):
//   xB[b][nt][cb][half][lane][8]  bf16(x/||x||) in MFMA A/B fragment order
//   sB[b][nt][cb][half][lane][8]  bf16(x @ W)   in MFMA B fragment order
//   (support computed with 16x16x32 bf16 MFMA; row norms computed in-block)
// ---------------------------------------------------------------------------
__global__ __launch_bounds__(256) void prep_xsb(
    const float* __restrict__ x, const float* __restrict__ w,
    unsigned short* __restrict__ xB, unsigned short* __restrict__ sB)
{
    __shared__ unsigned short xs[64 * 72];   // plain bf16 x tile
    __shared__ unsigned short xt[64 * 72];   // normalized bf16 x tile
    __shared__ unsigned short Wt[64 * 72];   // W transposed: Wt[e][k]
    __shared__ unsigned short st[64 * 72];   // support transposed: st[e][mrel]
    __shared__ float part[64][4];

    const int t = threadIdx.x;
    const int b = blockIdx.x >> 5, nt = blockIdx.x & 31;
    const int row = t >> 2, seg = t & 3;     // row 0..63, seg*16 = col offset

    // phase 1: load x row-chunk + W row-chunk, partial norms, stage xs & Wt
    float4 xq[4], wq[4];
    const float* xp = x + ((size_t)(b * NN + nt * 64 + row)) * 64 + seg * 16;
    const float* wp = w + row * 64 + seg * 16;
    #pragma unroll
    for (int i = 0; i < 4; ++i) { xq[i] = ((const float4*)xp)[i]; wq[i] = ((const float4*)wp)[i]; }
    float ss = 0.f;
    #pragma unroll
    for (int i = 0; i < 4; ++i)
        ss += xq[i].x * xq[i].x + xq[i].y * xq[i].y + xq[i].z * xq[i].z + xq[i].w * xq[i].w;
    part[row][seg] = ss;
    #pragma unroll
    for (int i = 0; i < 4; ++i) {
        ((unsigned int*)&xs[row * 72 + seg * 16])[i * 2]     = pk2(xq[i].x, xq[i].y);
        ((unsigned int*)&xs[row * 72 + seg * 16])[i * 2 + 1] = pk2(xq[i].z, xq[i].w);
        Wt[(seg * 16 + i * 4 + 0) * 72 + row] = f2b(wq[i].x);
        Wt[(seg * 16 + i * 4 + 1) * 72 + row] = f2b(wq[i].y);
        Wt[(seg * 16 + i * 4 + 2) * 72 + row] = f2b(wq[i].z);
        Wt[(seg * 16 + i * 4 + 3) * 72 + row] = f2b(wq[i].w);
    }
    __syncthreads();

    // phase 2: normalized tile
    const float rinv = 1.0f / sqrtf(part[row][0] + part[row][1] + part[row][2] + part[row][3]);
    #pragma unroll
    for (int i = 0; i < 4; ++i) {
        ((unsigned int*)&xt[row * 72 + seg * 16])[i * 2]     = pk2(xq[i].x * rinv, xq[i].y * rinv);
        ((unsigned int*)&xt[row * 72 + seg * 16])[i * 2 + 1] = pk2(xq[i].z * rinv, xq[i].w * rinv);
    }
    __syncthreads();

    // phase 3: frag extraction + support MFMA
    const int wv = t >> 6, l = t & 63, c = l & 15, q = l >> 4;
    {   // xB store (cb = wv): frag = xt[row=wv*16+c][k=q*8.. / 32+q*8..]
        bf8_t h0 = *(const bf8_t*)&xt[(wv * 16 + c) * 72 + q * 8];
        bf8_t h1 = *(const bf8_t*)&xt[(wv * 16 + c) * 72 + 32 + q * 8];
        unsigned short* base = xB + ((size_t)(b * 32 + nt)) * 4096 + wv * 1024 + l * 8;
        *(bf8_t*)base = h0;
        *(bf8_t*)(base + 512) = h1;
    }
    {   // support rows wv*16..+15: S = x @ W
        bf8_t a0 = *(const bf8_t*)&xs[(wv * 16 + c) * 72 + q * 8];
        bf8_t a1 = *(const bf8_t*)&xs[(wv * 16 + c) * 72 + 32 + q * 8];
        #pragma unroll
        for (int cb = 0; cb < 4; ++cb) {
            bf8_t b0 = *(const bf8_t*)&Wt[(cb * 16 + c) * 72 + q * 8];
            bf8_t b1 = *(const bf8_t*)&Wt[(cb * 16 + c) * 72 + 32 + q * 8];
            f32x4 z = (f32x4){0.f, 0.f, 0.f, 0.f};
            z = __builtin_amdgcn_mfma_f32_16x16x32_bf16(a0, b0, z, 0, 0, 0);
            z = __builtin_amdgcn_mfma_f32_16x16x32_bf16(a1, b1, z, 0, 0, 0);
            // C/D: row=q*4+r (S-row wv*16+q*4+r), col=cb*16+c (e) -> st[e][mrel]
            #pragma unroll
            for (int r = 0; r < 4; ++r)
                st[(cb * 16 + c) * 72 + wv * 16 + q * 4 + r] = f2b(z[r]);
        }
    }
    __syncthreads();

    // phase 4: sB store (cb = wv): frag = st[e=wv*16+c][mrel=q*8.. / 32+q*8..]
    {
        bf8_t h0 = *(const bf8_t*)&st[(wv * 16 + c) * 72 + q * 8];
        bf8_t h1 = *(const bf8_t*)&st[(wv * 16 + c) * 72 + 32 + q * 8];
        unsigned short* base = sB + ((size_t)(b * 32 + nt)) * 4096 + wv * 1024 + l * 8;
        *(bf8_t*)base = h0;
        *(bf8_t*)(base + 512) = h1;
    }
}

// ---------------------------------------------------------------------------
// prep_am: amB[it][mc][chunk j][lane][8] = bf16(att*mask), per-lane order
// matching gcn's mup^T C-layout: value v = cbm*16 + rbi*4 + r for lane (q,c):
//   i = it*64 + rbi*16 + c,  m = mc*64 + cbm*16 + q*4 + r
// Batch-independent: computed ONCE, reused by all 16 batches.
// ---------------------------------------------------------------------------
__global__ __launch_bounds__(256) void prep_am(
    const float* __restrict__ att, const int* __restrict__ mask,
    unsigned short* __restrict__ amB)
{
    __shared__ unsigned short amt[64 * 72];
    const int t = threadIdx.x;
    const int it = blockIdx.x >> 5, mc = blockIdx.x & 31;
    const int row = t >> 2, seg = t & 3;     // row = i-rel, cols = m-rel
    const size_t g = ((size_t)(it * 64 + row)) * NN + mc * 64 + seg * 16;
    #pragma unroll
    for (int i = 0; i < 4; ++i) {
        float4 a = *(const float4*)(att + g + i * 4);
        int4   m = *(const int4*)(mask + g + i * 4);
        ((unsigned int*)&amt[row * 72 + seg * 16])[i * 2] =
            pk2(a.x * (float)m.x, a.y * (float)m.y);
        ((unsigned int*)&amt[row * 72 + seg * 16])[i * 2 + 1] =
            pk2(a.z * (float)m.z, a.w * (float)m.w);
    }
    __syncthreads();
    const int wv = t >> 6, l = t & 63, c = l & 15, q = l >> 4;   // cbm = wv
    unsigned int ww[8];
    #pragma unroll
    for (int rbi = 0; rbi < 4; ++rbi) {
        #pragma unroll
        for (int rp = 0; rp < 2; ++rp) {
            unsigned int lo = amt[(rbi * 16 + c) * 72 + wv * 16 + q * 4 + rp * 2];
            unsigned int hi = amt[(rbi * 16 + c) * 72 + wv * 16 + q * 4 + rp * 2 + 1];
            ww[rbi * 2 + rp] = lo | (hi << 16);
        }
    }
    unsigned short* base = amB + ((size_t)(it * 32 + mc)) * 4096 + wv * 1024 + l * 8;
    *(uint4*)base         = *(uint4*)&ww[0];   // chunk wv*2   (rbi 0,1)
    *(uint4*)(base + 512) = *(uint4*)&ww[4];   // chunk wv*2+1 (rbi 2,3)
}

// ---------------------------------------------------------------------------
// gcn_kernel: block=(b, it); wave wm owns all 64 i-rows x m-chunks {wm+4t}.
// NO barriers in the loop: all operands are direct coalesced global loads in
// fragment order; Adj LDS is wave-private (same-wave DS ordering).
// mup^T = mfma(xm, xi) -> C cols contiguous in m -> b64 Adj writes (balanced
// banks with stride-72 padding). Epilogue: 2-phase cross-wave LDS reduction.
// ---------------------------------------------------------------------------
__global__ __launch_bounds__(256, 2) void gcn_kernel(
    const unsigned short* __restrict__ xB, const unsigned short* __restrict__ sB,
    const unsigned short* __restrict__ amB, const float* __restrict__ bias,
    float* __restrict__ out)
{
    __shared__ unsigned short Adj[4][64 * 72];   // 36,864 B; reused as fp32 red
    const int t = threadIdx.x;
    const int wm = t >> 6, l = t & 63, c = l & 15, q = l >> 4;
    const int b = blockIdx.x >> 5, it = blockIdx.x & 31;

    // loop-invariant xi-frags (B operand of GEMM1)
    const unsigned short* xit = xB + ((size_t)(b * 32 + it)) * 4096;
    bf8_t xi0[4], xi1[4];
    #pragma unroll
    for (int rb = 0; rb < 4; ++rb) {
        xi0[rb] = *(const bf8_t*)(xit + rb * 1024 + l * 8);
        xi1[rb] = *(const bf8_t*)(xit + rb * 1024 + 512 + l * 8);
    }
    f32x4 acc[4][4];
    #pragma unroll
    for (int rb = 0; rb < 4; ++rb)
        #pragma unroll
        for (int cb = 0; cb < 4; ++cb) acc[rb][cb] = (f32x4){0.f, 0.f, 0.f, 0.f};

    unsigned short* adj = &Adj[wm][0];

    for (int tt = 0; tt < 8; ++tt) {
        const int mc = wm + tt * 4;
        const unsigned short* xmt = xB + ((size_t)(b * 32 + mc)) * 4096;
        const unsigned short* smt = sB + ((size_t)(b * 32 + mc)) * 4096;
        const unsigned short* amp = amB + ((size_t)(it * 32 + mc)) * 4096;
        bf8_t xm0[4], xm1[4], sm0[4], sm1[4];
        uint4 amv[8];
        #pragma unroll
        for (int cb = 0; cb < 4; ++cb) {
            xm0[cb] = *(const bf8_t*)(xmt + cb * 1024 + l * 8);
            xm1[cb] = *(const bf8_t*)(xmt + cb * 1024 + 512 + l * 8);
        }
        #pragma unroll
        for (int cb = 0; cb < 4; ++cb) {
            sm0[cb] = *(const bf8_t*)(smt + cb * 1024 + l * 8);
            sm1[cb] = *(const bf8_t*)(smt + cb * 1024 + 512 + l * 8);
        }
        #pragma unroll
        for (int j = 0; j < 8; ++j) amv[j] = *(const uint4*)(amp + j * 512 + l * 8);

        // GEMM1: mup^T tile (m rows, i cols); norms pre-folded into xB
        #pragma unroll
        for (int cbm = 0; cbm < 4; ++cbm) {
            #pragma unroll
            for (int rbi = 0; rbi < 4; ++rbi) {
                f32x4 z = (f32x4){0.f, 0.f, 0.f, 0.f};
                z = __builtin_amdgcn_mfma_f32_16x16x32_bf16(xm0[cbm], xi0[rbi], z, 0, 0, 0);
                z = __builtin_amdgcn_mfma_f32_16x16x32_bf16(xm1[cbm], xi1[rbi], z, 0, 0, 0);
                const unsigned int w0 = ((const unsigned int*)&amv[cbm * 2 + (rbi >> 1)])[(rbi & 1) * 2 + 0];
                const unsigned int w1 = ((const unsigned int*)&amv[cbm * 2 + (rbi >> 1)])[(rbi & 1) * 2 + 1];
                const float a0f = __builtin_bit_cast(float, w0 << 16);
                const float a1f = __builtin_bit_cast(float, w0 & 0xFFFF0000u);
                const float a2f = __builtin_bit_cast(float, w1 << 16);
                const float a3f = __builtin_bit_cast(float, w1 & 0xFFFF0000u);
                uint2 p;
                p.x = pk2(z[0] * a0f, z[1] * a1f);
                p.y = pk2(z[2] * a2f, z[3] * a3f);
                // Adj[irel = rbi*16+c][mrel = cbm*16+q*4 .. +3], 8B-aligned b64
                *(uint2*)&adj[(rbi * 16 + c) * 72 + cbm * 16 + q * 4] = p;
            }
        }
        // GEMM2: out += Adj @ S  (A-frags from wave-private Adj; same-wave order)
        #pragma unroll
        for (int rb = 0; rb < 4; ++rb) {
            bf8_t p0 = *(const bf8_t*)&adj[(rb * 16 + c) * 72 + q * 8];
            bf8_t p1 = *(const bf8_t*)&adj[(rb * 16 + c) * 72 + 32 + q * 8];
            #pragma unroll
            for (int cb = 0; cb < 4; ++cb) {
                acc[rb][cb] = __builtin_amdgcn_mfma_f32_16x16x32_bf16(p0, sm0[cb], acc[rb][cb], 0, 0, 0);
                acc[rb][cb] = __builtin_amdgcn_mfma_f32_16x16x32_bf16(p1, sm1[cb], acc[rb][cb], 0, 0, 0);
            }
        }
    }

    // epilogue: cross-wave reduction (LDS reused as fp32), 2 halves of 32 rows
    float* red = (float*)&Adj[0][0];             // 4 regions x 2176 floats (stride 68)
    const int i0 = it * 64;
    for (int h = 0; h < 2; ++h) {
        __syncthreads();                          // loop Adj / prev-half reads done
        #pragma unroll
        for (int rb2 = 0; rb2 < 2; ++rb2) {
            const int rb = h * 2 + rb2;
            #pragma unroll
            for (int cb = 0; cb < 4; ++cb)
                #pragma unroll
                for (int r = 0; r < 4; ++r)
                    red[wm * 2176 + (rb2 * 16 + q * 4 + r) * 68 + cb * 16 + c] = acc[rb][cb][r];
        }
        __syncthreads();
        #pragma unroll
        for (int rnd = 0; rnd < 8; ++rnd) {
            const int idx = rnd * 256 + t;
            const int row = idx >> 6, col = idx & 63;
            const float s = red[0 * 2176 + row * 68 + col] + red[1 * 2176 + row * 68 + col]
                          + red[2 * 2176 + row * 68 + col] + red[3 * 2176 + row * 68 + col];
            out[((size_t)(b * NN + i0 + h * 32 + row)) * 64 + col] = s + bias[col];
        }
    }
}

extern "C" void kernel_launch(void* const* d_in, const int* in_sizes, int n_in,
                              void* d_out, int out_size, void* d_ws, size_t ws_size,
                              hipStream_t stream) {
    const float* x    = (const float*)d_in[0];   // [16,2048,64]
    const float* w    = (const float*)d_in[1];   // [64,64]
    const float* att  = (const float*)d_in[2];   // [2048,2048]
    const float* bias = (const float*)d_in[3];   // [64]
    const int*   mask = (const int*)d_in[4];     // [2048,2048]
    float* out = (float*)d_out;                  // [16,2048,64]

    // ws: xB 4 MB | sB 4 MB | amB 8 MB  (16 MB total)
    unsigned short* xB  = (unsigned short*)d_ws;
    unsigned short* sB  = xB + (size_t)2 * 1024 * 1024;
    unsigned short* amB = sB + (size_t)2 * 1024 * 1024;

    prep_xsb<<<dim3(512), dim3(256), 0, stream>>>(x, w, xB, sB);
    prep_am<<<dim3(1024), dim3(256), 0, stream>>>(att, mask, amB);
    gcn_kernel<<<dim3(512), dim3(256), 0, stream>>>(xB, sB, amB, bias, out);
}